// Round 3
// baseline (193.439 us; speedup 1.0000x reference)
//
#include <hip/hip_runtime.h>
#include <math.h>

#define NN 8192
#define L2E 1.44269504088896340736f
#define TWO_PI 6.28318530717958647693f

typedef _Float16 h8 __attribute__((ext_vector_type(8)));
typedef _Float16 h4 __attribute__((ext_vector_type(4)));
typedef float f32x4 __attribute__((ext_vector_type(4)));
typedef float f32x2 __attribute__((ext_vector_type(2)));
#define MFMA16(A, B, C) __builtin_amdgcn_mfma_f32_16x16x32_f16(A, B, C, 0, 0, 0)

// async 16B-per-lane global->LDS DMA; LDS dest is wave-uniform base + lane*16
#define GLD_LDS16(gsrc, ldst)                                          \
  __builtin_amdgcn_global_load_lds(                                    \
      (const __attribute__((address_space(1))) unsigned int*)(gsrc),   \
      (__attribute__((address_space(3))) unsigned int*)(ldst), 16, 0, 0)

union V8 { float4 v[2]; float f[8]; };

// ---------------------------------------------------------------------------
// prep: eta_s = eta*s, phi_s = phi*s (s = sqrt(alpha*log2e));
// H1 = relu(x@W1+b1) f32 row-major + f16 transposed [64][NN]. 32 rows/block.
// ---------------------------------------------------------------------------
__global__ __launch_bounds__(256) void prep_kernel(
    const float* __restrict__ x, const float* __restrict__ alpha,
    const float* __restrict__ W1, const float* __restrict__ b1,
    float* __restrict__ eta_s, float* __restrict__ phi_s,
    float* __restrict__ H1, _Float16* __restrict__ HT1,
    float* __restrict__ svec)
{
  __shared__ float sW[448];
  __shared__ float sb[64];
  __shared__ float T[32][68];
  const int t = threadIdx.x;
  if (blockIdx.x == 0 && t < 64) svec[t] = 0.f;
  for (int k = t; k < 448; k += 256) sW[k] = W1[k];
  if (t < 64) sb[t] = b1[t];
  const float s = sqrtf(alpha[0] * L2E);
  const int i0 = blockIdx.x * 32;
  const int r = t >> 3, q = t & 7;
  const int i = i0 + r;
  float xv[7];
#pragma unroll
  for (int k = 0; k < 7; k++) xv[k] = x[i * 7 + k];
  if (q == 0) { eta_s[i] = xv[1] * s; phi_s[i] = xv[2] * s; }
  __syncthreads();
#pragma unroll
  for (int c = 0; c < 8; c++) {
    const int n = q * 8 + c;
    float hv = sb[n];
#pragma unroll
    for (int k = 0; k < 7; k++) hv = fmaf(xv[k], sW[k * 64 + n], hv);
    T[r][n] = fmaxf(hv, 0.f);
  }
  __syncthreads();
  for (int e = t; e < 512; e += 256)
    *(f32x4*)(H1 + (size_t)i0 * 64 + (e << 2)) =
        *(const f32x4*)&T[e >> 4][(e << 2) & 63];
  const int n = t >> 2, sg = (t & 3) * 8;
  h8 v;
#pragma unroll
  for (int ss = 0; ss < 8; ss++) v[ss] = (_Float16)T[sg + ss][n];
  *(h8*)(HT1 + (size_t)n * NN + i0 + sg) = v;
}

// ---------------------------------------------------------------------------
// attn: 32 i-rows/block, 4-way j-split (grid 1024). 16 stages of 128 j.
// WAVE-PRIVATE double-buffered LDS staging (8 KB/wave): each wave stages only
// its own j-slice via global_load_lds (identity layout: call k stages the
// exact 16B units read back as frag k -> lane-linear ds_read_b128, conflict-
// free). NO barriers in the main loop; sync is counted s_waitcnt vmcnt(8)
// (one 8-op VMEM group per stage, order pinned by sched_barrier(0)).
// l (P row-sums) accumulated via extra MFMA with ones B-frag.
// ---------------------------------------------------------------------------
template <bool NEED_L>
__global__ __launch_bounds__(256, 4) void attn_pass(
    const float* __restrict__ eta_s, const float* __restrict__ phi_s,
    const _Float16* __restrict__ HT, const float* __restrict__ alpha,
    float* __restrict__ Ypart, float* __restrict__ lpart)
{
  __shared__ __align__(16) char smem[32768];  // 4 waves x 2 bufs x 4 KB
  const int tid = threadIdx.x;
  const int w = tid >> 6, lane = tid & 63, m = lane & 15, g = lane >> 4;
  const int tile = blockIdx.x >> 2, part = blockIdx.x & 3;
  const int i0 = tile << 5;
  const int jbase = part << 11;
  const float Cs = TWO_PI * sqrtf(alpha[0] * L2E);
  const float et0 = eta_s[i0 + m],      ph0 = phi_s[i0 + m];
  const float et1 = eta_s[i0 + 16 + m], ph1 = phi_s[i0 + 16 + m];

  // per-lane global source: frag k of stage s = HT[(m+16k)][joff + s*128 ..+8]
  const int joff = jbase + (w << 5) + (g << 3);
  const _Float16* hb = HT + (size_t)m * NN + joff;
  const float* ep = eta_s + joff;
  const float* pp = phi_s + joff;

  // wave-private slab: buf b at smem + w*8192 + b*4096; call k -> +k*1024.
  // GLD dest base is wave-uniform; HW adds lane*16. Read-back of frag k:
  // same address + lane*16 -> perfectly linear.
  char* const slab = smem + (w << 13);

  f32x4 a00 = {0,0,0,0}, a01 = {0,0,0,0}, a02 = {0,0,0,0}, a03 = {0,0,0,0};
  f32x4 a10 = {0,0,0,0}, a11 = {0,0,0,0}, a12 = {0,0,0,0}, a13 = {0,0,0,0};
  f32x4 l0a = {0,0,0,0}, l1a = {0,0,0,0};
  const h8 onesv = {(_Float16)1.f, (_Float16)1.f, (_Float16)1.f, (_Float16)1.f,
                    (_Float16)1.f, (_Float16)1.f, (_Float16)1.f, (_Float16)1.f};

  V8 Eb[2], Pb[2];

  // prologue group(-1): GLD(stage 0) x4 + EP(0) x4, order pinned.
#pragma unroll
  for (int k = 0; k < 4; ++k)
    GLD_LDS16(hb + (size_t)k * 16 * NN, slab + (k << 10));
  Eb[0].v[0] = *(const float4*)(ep);     Eb[0].v[1] = *(const float4*)(ep + 4);
  Pb[0].v[0] = *(const float4*)(pp);     Pb[0].v[1] = *(const float4*)(pp + 4);
  __builtin_amdgcn_sched_barrier(0);

  union AF { h8 v; decltype(__builtin_amdgcn_cvt_pkrtz(0.f, 0.f)) p[4]; };

#pragma unroll
  for (int s = 0; s < 16; ++s) {
    // group(s): issue stage s+1 (8 VMEM ops), pinned before the wait.
    if (s < 15) {
      char* const nb = slab + (((s + 1) & 1) << 12);
      const _Float16* src = hb + (s + 1) * 128;
#pragma unroll
      for (int k = 0; k < 4; ++k)
        GLD_LDS16(src + (size_t)k * 16 * NN, nb + (k << 10));
      Eb[(s + 1) & 1].v[0] = *(const float4*)(ep + (s + 1) * 128);
      Eb[(s + 1) & 1].v[1] = *(const float4*)(ep + (s + 1) * 128 + 4);
      Pb[(s + 1) & 1].v[0] = *(const float4*)(pp + (s + 1) * 128);
      Pb[(s + 1) & 1].v[1] = *(const float4*)(pp + (s + 1) * 128 + 4);
    }
    __builtin_amdgcn_sched_barrier(0);
    // stage-s data (group(s-1)) ready when <= 8 newer VMEM ops outstanding.
    if (s < 15) asm volatile("s_waitcnt vmcnt(8)" ::: "memory");
    else        asm volatile("s_waitcnt vmcnt(0)" ::: "memory");
    __builtin_amdgcn_sched_barrier(0);

    const char* fb = slab + ((s & 1) << 12) + (lane << 4);
    const h8 b0 = *(const h8*)(fb);
    const h8 b1 = *(const h8*)(fb + 1024);
    const h8 b2 = *(const h8*)(fb + 2048);
    const h8 b3 = *(const h8*)(fb + 3072);
    const V8& E = Eb[s & 1];
    const V8& P = Pb[s & 1];

    AF af0, af1;
#pragma unroll
    for (int tt = 0; tt < 8; tt += 2) {
      const f32x2 pj = {P.f[tt], P.f[tt + 1]};
      const f32x2 ej = {E.f[tt], E.f[tt + 1]};
      const f32x2 dp0 = ph0 - pj, dp1 = ph1 - pj;
      const f32x2 ad0 = {fabsf(dp0.x), fabsf(dp0.y)};
      const f32x2 ad1 = {fabsf(dp1.x), fabsf(dp1.y)};
      const f32x2 cm0 = Cs - ad0, cm1 = Cs - ad1;
      const f32x2 wr0 = {fminf(ad0.x, cm0.x), fminf(ad0.y, cm0.y)};
      const f32x2 wr1 = {fminf(ad1.x, cm1.x), fminf(ad1.y, cm1.y)};
      const f32x2 de0 = et0 - ej, de1 = et1 - ej;
      const f32x2 r20 = de0 * de0 + wr0 * wr0;
      const f32x2 r21 = de1 * de1 + wr1 * wr1;
      const f32x2 ax0 = {__builtin_amdgcn_exp2f(-r20.x),
                         __builtin_amdgcn_exp2f(-r20.y)};
      const f32x2 ax1 = {__builtin_amdgcn_exp2f(-r21.x),
                         __builtin_amdgcn_exp2f(-r21.y)};
      const f32x2 ga0 = ax0 * L2E - L2E;
      const f32x2 ga1 = ax1 * L2E - L2E;
      af0.p[tt >> 1] = __builtin_amdgcn_cvt_pkrtz(
          __builtin_amdgcn_exp2f(ga0.x), __builtin_amdgcn_exp2f(ga0.y));
      af1.p[tt >> 1] = __builtin_amdgcn_cvt_pkrtz(
          __builtin_amdgcn_exp2f(ga1.x), __builtin_amdgcn_exp2f(ga1.y));
    }
    a00 = MFMA16(af0.v, b0, a00); a01 = MFMA16(af0.v, b1, a01);
    a02 = MFMA16(af0.v, b2, a02); a03 = MFMA16(af0.v, b3, a03);
    a10 = MFMA16(af1.v, b0, a10); a11 = MFMA16(af1.v, b1, a11);
    a12 = MFMA16(af1.v, b2, a12); a13 = MFMA16(af1.v, b3, a13);
    if constexpr (NEED_L) {
      l0a = MFMA16(af0.v, onesv, l0a);
      l1a = MFMA16(af1.v, onesv, l1a);
    }
  }

  __syncthreads();  // all waves done with private slabs; reuse smem for red

  // cross-wave reduction. D layout: col = lane&15, row = (lane>>4)*4 + reg.
  // Col 64 carries l (= rowsum from ones-MFMA; identical across lanes m).
  typedef float Red2[32][66];
  Red2* red = (Red2*)smem;
  const int h = w >> 1;
  if ((w & 1) == 0) {
#pragma unroll
    for (int r = 0; r < 4; ++r) {
      red[h][g * 4 + r][m]      = a00[r]; red[h][g * 4 + r][16 + m] = a01[r];
      red[h][g * 4 + r][32 + m] = a02[r]; red[h][g * 4 + r][48 + m] = a03[r];
      red[h][16 + g * 4 + r][m]      = a10[r]; red[h][16 + g * 4 + r][16 + m] = a11[r];
      red[h][16 + g * 4 + r][32 + m] = a12[r]; red[h][16 + g * 4 + r][48 + m] = a13[r];
    }
    if constexpr (NEED_L) {
      if (m == 0) {
#pragma unroll
        for (int r = 0; r < 4; ++r) {
          red[h][g * 4 + r][64]      = l0a[r];
          red[h][16 + g * 4 + r][64] = l1a[r];
        }
      }
    }
  }
  __syncthreads();
  if (w & 1) {
#pragma unroll
    for (int r = 0; r < 4; ++r) {
      red[h][g * 4 + r][m]      += a00[r]; red[h][g * 4 + r][16 + m] += a01[r];
      red[h][g * 4 + r][32 + m] += a02[r]; red[h][g * 4 + r][48 + m] += a03[r];
      red[h][16 + g * 4 + r][m]      += a10[r]; red[h][16 + g * 4 + r][16 + m] += a11[r];
      red[h][16 + g * 4 + r][32 + m] += a12[r]; red[h][16 + g * 4 + r][48 + m] += a13[r];
    }
    if constexpr (NEED_L) {
      if (m == 0) {
#pragma unroll
        for (int r = 0; r < 4; ++r) {
          red[h][g * 4 + r][64]      += l0a[r];
          red[h][16 + g * 4 + r][64] += l1a[r];
        }
      }
    }
  }
  __syncthreads();
#pragma unroll
  for (int k = 0; k < 8; ++k) {
    const int e = tid + k * 256;
    Ypart[((size_t)part * NN + i0 + (e >> 6)) * 64 + (e & 63)] =
        red[0][e >> 6][e & 63] + red[1][e >> 6][e & 63];
  }
  if constexpr (NEED_L) {
    if (tid < 32)
      lpart[(size_t)part * NN + i0 + tid] = red[0][tid][64] + red[1][tid][64];
  }
}

// ---------------------------------------------------------------------------
// mid: U = sum(Ypart)/l + H1 ; Z = relu(U@wt1+bs1) ; H2 = relu(Z@W2+b2)
// 16 rows/block, grid 512. U rows read as ds_read_b128 (U padded to [68]).
// ---------------------------------------------------------------------------
__global__ __launch_bounds__(256) void mid_kernel(
    const float* __restrict__ Yp, const float* __restrict__ lp,
    const float* __restrict__ H1, const float* __restrict__ wt1,
    const float* __restrict__ bs1, const float* __restrict__ W2,
    const float* __restrict__ b2, float* __restrict__ H2,
    _Float16* __restrict__ HT2)
{
  __shared__ float sA[64][68];
  __shared__ float sB[64][68];
  __shared__ float U[16][68];
  __shared__ float sb2v[64];
  const int t = threadIdx.x;
  for (int e = t; e < 1024; e += 256) {
    const int rr = e >> 4, cc = (e << 2) & 63;
    *(f32x4*)&sA[rr][cc] = *(const f32x4*)(wt1 + (e << 2));
    *(f32x4*)&sB[rr][cc] = *(const f32x4*)(W2 + (e << 2));
  }
  if (t < 64) sb2v[t] = b2[t];
  const float bsv = bs1[0];
  const int i0 = blockIdx.x * 16;
  const int r = t >> 4, q = t & 15;
  const int i = i0 + r;
  float l = 0.f;
#pragma unroll
  for (int p = 0; p < 4; ++p) l += lp[(size_t)p * NN + i];
  const float rl = 1.0f / l;
  f32x4 ya = {0, 0, 0, 0};
#pragma unroll
  for (int p = 0; p < 4; ++p)
    ya += *(const f32x4*)(Yp + ((size_t)p * NN + i) * 64 + q * 4);
  const f32x4 h1 = *(const f32x4*)(H1 + (size_t)i * 64 + q * 4);
#pragma unroll
  for (int c = 0; c < 4; ++c) U[r][q * 4 + c] = fmaf(ya[c], rl, h1[c]);
  __syncthreads();
  float z[4];
#pragma unroll
  for (int c = 0; c < 4; ++c) z[c] = bsv;
#pragma unroll
  for (int k4 = 0; k4 < 64; k4 += 4) {
    const f32x4 u4 = *(const f32x4*)&U[r][k4];
#pragma unroll
    for (int kk = 0; kk < 4; ++kk) {
      const f32x4 sa = *(const f32x4*)&sA[k4 + kk][q * 4];
#pragma unroll
      for (int c = 0; c < 4; ++c) z[c] = fmaf(u4[kk], sa[c], z[c]);
    }
  }
  __syncthreads();
#pragma unroll
  for (int c = 0; c < 4; ++c) U[r][q * 4 + c] = fmaxf(z[c], 0.f);
  __syncthreads();
  float hv[4];
#pragma unroll
  for (int c = 0; c < 4; ++c) hv[c] = sb2v[q * 4 + c];
#pragma unroll
  for (int k4 = 0; k4 < 64; k4 += 4) {
    const f32x4 u4 = *(const f32x4*)&U[r][k4];
#pragma unroll
    for (int kk = 0; kk < 4; ++kk) {
      const f32x4 sb4 = *(const f32x4*)&sB[k4 + kk][q * 4];
#pragma unroll
      for (int c = 0; c < 4; ++c) hv[c] = fmaf(u4[kk], sb4[c], hv[c]);
    }
  }
  __syncthreads();
#pragma unroll
  for (int c = 0; c < 4; ++c) U[r][q * 4 + c] = fmaxf(hv[c], 0.f);
  __syncthreads();
  *(f32x4*)(H2 + (size_t)i0 * 64 + (t << 2)) =
      *(const f32x4*)&U[t >> 4][(t << 2) & 63];
  const int n = t >> 2, sg = (t & 3) * 4;
  h4 v;
#pragma unroll
  for (int ss = 0; ss < 4; ss++) v[ss] = (_Float16)U[sg + ss][n];
  *(h4*)(HT2 + (size_t)n * NN + i0 + sg) = v;
}

// ---------------------------------------------------------------------------
// final: V = relu((sum(Ypart)/l + H2)@wt2 + bs2); column sums -> atomicAdd.
// ---------------------------------------------------------------------------
__global__ __launch_bounds__(256) void final_kernel(
    const float* __restrict__ Yp, const float* __restrict__ lp,
    const float* __restrict__ H2, const float* __restrict__ wt2,
    const float* __restrict__ bs2, float* __restrict__ svec)
{
  __shared__ float sA[64][68];
  __shared__ float U[16][68];
  __shared__ float cred[4][64];
  const int t = threadIdx.x;
  for (int e = t; e < 1024; e += 256) {
    const int rr = e >> 4, cc = (e << 2) & 63;
    *(f32x4*)&sA[rr][cc] = *(const f32x4*)(wt2 + (e << 2));
  }
  const float bsv = bs2[0];
  const int i0 = blockIdx.x * 16;
  const int r = t >> 4, q = t & 15;
  const int i = i0 + r;
  float l = 0.f;
#pragma unroll
  for (int p = 0; p < 4; ++p) l += lp[(size_t)p * NN + i];
  const float rl = 1.0f / l;
  f32x4 ya = {0, 0, 0, 0};
#pragma unroll
  for (int p = 0; p < 4; ++p)
    ya += *(const f32x4*)(Yp + ((size_t)p * NN + i) * 64 + q * 4);
  const f32x4 h2 = *(const f32x4*)(H2 + (size_t)i * 64 + q * 4);
#pragma unroll
  for (int c = 0; c < 4; ++c) U[r][q * 4 + c] = fmaf(ya[c], rl, h2[c]);
  __syncthreads();
  float z[4];
#pragma unroll
  for (int c = 0; c < 4; ++c) z[c] = bsv;
#pragma unroll
  for (int k4 = 0; k4 < 64; k4 += 4) {
    const f32x4 u4 = *(const f32x4*)&U[r][k4];
#pragma unroll
    for (int kk = 0; kk < 4; ++kk) {
      const f32x4 sa = *(const f32x4*)&sA[k4 + kk][q * 4];
#pragma unroll
      for (int c = 0; c < 4; ++c) z[c] = fmaf(u4[kk], sa[c], z[c]);
    }
  }
  __syncthreads();
#pragma unroll
  for (int c = 0; c < 4; ++c) U[r][q * 4 + c] = fmaxf(z[c], 0.f);
  __syncthreads();
  const int col = t & 63, rg = t >> 6;
  float ps = 0.f;
#pragma unroll
  for (int rr = 0; rr < 4; rr++) ps += U[rg * 4 + rr][col];
  cred[rg][col] = ps;
  __syncthreads();
  if (t < 64)
    atomicAdd(svec + t, cred[0][t] + cred[1][t] + cred[2][t] + cred[3][t]);
}

__global__ void out_kernel(const float* __restrict__ svec,
                           const float* __restrict__ Wl,
                           const float* __restrict__ bl,
                           float* __restrict__ out)
{
  const int t = threadIdx.x;  // 64 threads
  float v = svec[t] * Wl[t];
#pragma unroll
  for (int off = 32; off > 0; off >>= 1) v += __shfl_down(v, off);
  if (t == 0) {
    const float logit = v + bl[0];
    out[0] = 1.0f / (1.0f + __builtin_amdgcn_exp2f(-logit * L2E));
  }
}

extern "C" void kernel_launch(void* const* d_in, const int* in_sizes, int n_in,
                              void* d_out, int out_size, void* d_ws,
                              size_t ws_size, hipStream_t stream)
{
  const float* x     = (const float*)d_in[0];
  const float* alpha = (const float*)d_in[1];
  const float* W1    = (const float*)d_in[2];
  const float* b1    = (const float*)d_in[3];
  const float* wt1   = (const float*)d_in[4];
  const float* bs1   = (const float*)d_in[5];
  const float* W2    = (const float*)d_in[6];
  const float* b2    = (const float*)d_in[7];
  const float* wt2   = (const float*)d_in[8];
  const float* bs2   = (const float*)d_in[9];
  const float* Wl    = (const float*)d_in[10];
  const float* bl    = (const float*)d_in[11];
  float* out = (float*)d_out;

  char* ws = (char*)d_ws;
  size_t off = 0;
  auto alloc = [&](size_t bytes) {
    void* p = ws + off;
    off = (off + bytes + 255) & ~(size_t)255;
    return p;
  };
  float* eta_s = (float*)alloc(NN * 4 + 256);
  float* phi_s = (float*)alloc(NN * 4 + 256);
  float* H1    = (float*)alloc((size_t)NN * 64 * 4);
  float* H2    = (float*)alloc((size_t)NN * 64 * 4);
  float* Ypart = (float*)alloc((size_t)4 * NN * 64 * 4);   // 8 MB
  float* lpart = (float*)alloc((size_t)4 * NN * 4);
  _Float16* HT = (_Float16*)alloc((size_t)NN * 64 * 2 + 512);
  float* svec  = (float*)alloc(64 * 4);

  prep_kernel<<<256, 256, 0, stream>>>(x, alpha, W1, b1, eta_s, phi_s, H1, HT, svec);
  attn_pass<true><<<1024, 256, 0, stream>>>(eta_s, phi_s, HT, alpha, Ypart, lpart);
  mid_kernel<<<512, 256, 0, stream>>>(Ypart, lpart, H1, wt1, bs1, W2, b2, H2, HT);
  attn_pass<false><<<1024, 256, 0, stream>>>(eta_s, phi_s, HT, alpha, Ypart, nullptr);
  final_kernel<<<512, 256, 0, stream>>>(Ypart, lpart, H2, wt2, bs2, svec);
  out_kernel<<<1, 64, 0, stream>>>(svec, Wl, bl, out);
}

// Round 4
// 185.724 us; speedup vs baseline: 1.0415x; 1.0415x over previous
//
#include <hip/hip_runtime.h>
#include <math.h>

#define NN 8192
#define L2E 1.44269504088896340736f
#define TWO_PI 6.28318530717958647693f

typedef _Float16 h8 __attribute__((ext_vector_type(8)));
typedef _Float16 h4 __attribute__((ext_vector_type(4)));
typedef float f32x4 __attribute__((ext_vector_type(4)));
typedef float f32x2 __attribute__((ext_vector_type(2)));
#define MFMA16(A, B, C) __builtin_amdgcn_mfma_f32_16x16x32_f16(A, B, C, 0, 0, 0)

// async 16B-per-lane global->LDS DMA; LDS dest is wave-uniform base + lane*16
#define GLD_LDS16(gsrc, ldst)                                          \
  __builtin_amdgcn_global_load_lds(                                    \
      (const __attribute__((address_space(1))) unsigned int*)(gsrc),   \
      (__attribute__((address_space(3))) unsigned int*)(ldst), 16, 0, 0)

union V8 { float4 v[2]; float f[8]; };

// ---------------------------------------------------------------------------
// prep: eta_s = eta*s, phi_s = phi*s (s = sqrt(alpha*log2e));
// H1 = relu(x@W1+b1) f32 row-major + f16 transposed [64][NN]. 32 rows/block.
// ---------------------------------------------------------------------------
__global__ __launch_bounds__(256) void prep_kernel(
    const float* __restrict__ x, const float* __restrict__ alpha,
    const float* __restrict__ W1, const float* __restrict__ b1,
    float* __restrict__ eta_s, float* __restrict__ phi_s,
    float* __restrict__ H1, _Float16* __restrict__ HT1,
    float* __restrict__ svec)
{
  __shared__ float sW[448];
  __shared__ float sb[64];
  __shared__ float T[32][68];
  const int t = threadIdx.x;
  if (blockIdx.x == 0 && t < 64) svec[t] = 0.f;
  for (int k = t; k < 448; k += 256) sW[k] = W1[k];
  if (t < 64) sb[t] = b1[t];
  const float s = sqrtf(alpha[0] * L2E);
  const int i0 = blockIdx.x * 32;
  const int r = t >> 3, q = t & 7;
  const int i = i0 + r;
  float xv[7];
#pragma unroll
  for (int k = 0; k < 7; k++) xv[k] = x[i * 7 + k];
  if (q == 0) { eta_s[i] = xv[1] * s; phi_s[i] = xv[2] * s; }
  __syncthreads();
#pragma unroll
  for (int c = 0; c < 8; c++) {
    const int n = q * 8 + c;
    float hv = sb[n];
#pragma unroll
    for (int k = 0; k < 7; k++) hv = fmaf(xv[k], sW[k * 64 + n], hv);
    T[r][n] = fmaxf(hv, 0.f);
  }
  __syncthreads();
  for (int e = t; e < 512; e += 256)
    *(f32x4*)(H1 + (size_t)i0 * 64 + (e << 2)) =
        *(const f32x4*)&T[e >> 4][(e << 2) & 63];
  const int n = t >> 2, sg = (t & 3) * 8;
  h8 v;
#pragma unroll
  for (int ss = 0; ss < 8; ss++) v[ss] = (_Float16)T[sg + ss][n];
  *(h8*)(HT1 + (size_t)n * NN + i0 + sg) = v;
}

// ---------------------------------------------------------------------------
// attn: 32 i-rows/block, 8-way j-split (grid 2048). 8 stages of 128 j.
// Wave-private double-buffered LDS slabs (2 x 4 KB/wave) staged via
// global_load_lds; eta/phi preloaded to LDS once (out of the vmcnt domain).
// NO block barriers in the loop: the only VMEM ops are the 4 GLDs/stage,
// pinned by a single asm-with-memory-clobber wall per stage, so
// s_waitcnt vmcnt(4) exactly retires the previous stage's slab. Plain
// ds_read_b128 for frags (compiler tracks lgkmcnt). Waves drift freely ->
// stalls decorrelate across the 16 waves/CU.
// l (P row-sums) accumulated via extra MFMA with ones B-frag.
// ---------------------------------------------------------------------------
template <bool NEED_L>
__global__ __launch_bounds__(256, 4)
__attribute__((amdgpu_waves_per_eu(4, 4))) void attn_pass(
    const float* __restrict__ eta_s, const float* __restrict__ phi_s,
    const _Float16* __restrict__ HT, const float* __restrict__ alpha,
    float* __restrict__ Ypart, float* __restrict__ lpart)
{
  // [0,4096) eL | [4096,8192) pL | [8192,40960) 4 waves x 2 bufs x 4 KB
  __shared__ __align__(16) char smem[40960];
  float* const eL = (float*)smem;
  float* const pL = (float*)(smem + 4096);
  const int tid = threadIdx.x;
  const int w = tid >> 6, lane = tid & 63, m = lane & 15, g = lane >> 4;
  const int tile = blockIdx.x >> 3, part = blockIdx.x & 7;
  const int i0 = tile << 5;
  const int jbase = part << 10;
  const float Cs = TWO_PI * sqrtf(alpha[0] * L2E);
  const float et0 = eta_s[i0 + m],      ph0 = phi_s[i0 + m];
  const float et1 = eta_s[i0 + 16 + m], ph1 = phi_s[i0 + 16 + m];

  // preload block's eta/phi j-range (1024 each) into LDS, coalesced.
  *(f32x4*)&eL[tid * 4] = *(const f32x4*)(eta_s + jbase + tid * 4);
  *(f32x4*)&pL[tid * 4] = *(const f32x4*)(phi_s + jbase + tid * 4);

  // per-lane GLD source: frag k of stage s = HT[m+16k][jbase + s*128 + w*32 + g*8]
  const _Float16* hb = HT + (size_t)m * NN + jbase + (w << 5) + (g << 3);
  // wave-private slab; GLD dest = wave-uniform base + lane*16 (identity
  // layout: read-back of frag k is the same address + lane*16 -> linear).
  char* const slab = smem + 8192 + (w << 13);

  f32x4 a00 = {0,0,0,0}, a01 = {0,0,0,0}, a02 = {0,0,0,0}, a03 = {0,0,0,0};
  f32x4 a10 = {0,0,0,0}, a11 = {0,0,0,0}, a12 = {0,0,0,0}, a13 = {0,0,0,0};
  f32x4 l0a = {0,0,0,0}, l1a = {0,0,0,0};
  const h8 onesv = {(_Float16)1.f, (_Float16)1.f, (_Float16)1.f, (_Float16)1.f,
                    (_Float16)1.f, (_Float16)1.f, (_Float16)1.f, (_Float16)1.f};

  __syncthreads();  // eL/pL visible; also drains all prior VMEM (vmcnt=0)

  // prologue: stage 0 -> buf 0
#pragma unroll
  for (int k = 0; k < 4; ++k)
    GLD_LDS16(hb + (size_t)k * 16 * NN, slab + (k << 10));

  union AF { h8 v; decltype(__builtin_amdgcn_cvt_pkrtz(0.f, 0.f)) p[4]; };

#pragma unroll
  for (int s = 0; s < 8; ++s) {
    if (s < 7) {  // issue stage s+1 into the other buffer (4 VMEM ops)
      char* const nb = slab + (((s + 1) & 1) << 12);
      const _Float16* src = hb + (s + 1) * 128;
#pragma unroll
      for (int k = 0; k < 4; ++k)
        GLD_LDS16(src + (size_t)k * 16 * NN, nb + (k << 10));
    }
    // wall: memory clobber pins GLDs on their side; vmcnt(4) retires stage s.
    if (s < 7) asm volatile("s_waitcnt vmcnt(4)" ::: "memory");
    else       asm volatile("s_waitcnt vmcnt(0)" ::: "memory");

    const char* fb = slab + ((s & 1) << 12) + (lane << 4);
    const h8 b0 = *(const h8*)(fb);
    const h8 b1 = *(const h8*)(fb + 1024);
    const h8 b2 = *(const h8*)(fb + 2048);
    const h8 b3 = *(const h8*)(fb + 3072);
    const int o = s * 128 + (w << 5) + (g << 3);
    V8 E, P;
    E.v[0] = *(const float4*)&eL[o]; E.v[1] = *(const float4*)&eL[o + 4];
    P.v[0] = *(const float4*)&pL[o]; P.v[1] = *(const float4*)&pL[o + 4];

    AF af0, af1;
#pragma unroll
    for (int tt = 0; tt < 8; tt += 2) {
      const f32x2 pj = {P.f[tt], P.f[tt + 1]};
      const f32x2 ej = {E.f[tt], E.f[tt + 1]};
      const f32x2 dp0 = ph0 - pj, dp1 = ph1 - pj;
      const f32x2 ad0 = {fabsf(dp0.x), fabsf(dp0.y)};
      const f32x2 ad1 = {fabsf(dp1.x), fabsf(dp1.y)};
      const f32x2 cm0 = Cs - ad0, cm1 = Cs - ad1;
      const f32x2 wr0 = {fminf(ad0.x, cm0.x), fminf(ad0.y, cm0.y)};
      const f32x2 wr1 = {fminf(ad1.x, cm1.x), fminf(ad1.y, cm1.y)};
      const f32x2 de0 = et0 - ej, de1 = et1 - ej;
      const f32x2 r20 = de0 * de0 + wr0 * wr0;
      const f32x2 r21 = de1 * de1 + wr1 * wr1;
      const f32x2 ax0 = {__builtin_amdgcn_exp2f(-r20.x),
                         __builtin_amdgcn_exp2f(-r20.y)};
      const f32x2 ax1 = {__builtin_amdgcn_exp2f(-r21.x),
                         __builtin_amdgcn_exp2f(-r21.y)};
      const f32x2 ga0 = ax0 * L2E - L2E;
      const f32x2 ga1 = ax1 * L2E - L2E;
      af0.p[tt >> 1] = __builtin_amdgcn_cvt_pkrtz(
          __builtin_amdgcn_exp2f(ga0.x), __builtin_amdgcn_exp2f(ga0.y));
      af1.p[tt >> 1] = __builtin_amdgcn_cvt_pkrtz(
          __builtin_amdgcn_exp2f(ga1.x), __builtin_amdgcn_exp2f(ga1.y));
    }
    a00 = MFMA16(af0.v, b0, a00); a01 = MFMA16(af0.v, b1, a01);
    a02 = MFMA16(af0.v, b2, a02); a03 = MFMA16(af0.v, b3, a03);
    a10 = MFMA16(af1.v, b0, a10); a11 = MFMA16(af1.v, b1, a11);
    a12 = MFMA16(af1.v, b2, a12); a13 = MFMA16(af1.v, b3, a13);
    if constexpr (NEED_L) {
      l0a = MFMA16(af0.v, onesv, l0a);
      l1a = MFMA16(af1.v, onesv, l1a);
    }
  }

  __syncthreads();  // all waves done with slabs/eL/pL; reuse smem for red

  // cross-wave reduction. D layout: col = lane&15, row = (lane>>4)*4 + reg.
  // Col 64 carries l (= rowsum from ones-MFMA; identical across lanes m).
  typedef float Red2[32][66];
  Red2* red = (Red2*)smem;  // 2 x 8448 B = 16896 <= 40960
  const int h = w >> 1;
  if ((w & 1) == 0) {
#pragma unroll
    for (int r = 0; r < 4; ++r) {
      red[h][g * 4 + r][m]      = a00[r]; red[h][g * 4 + r][16 + m] = a01[r];
      red[h][g * 4 + r][32 + m] = a02[r]; red[h][g * 4 + r][48 + m] = a03[r];
      red[h][16 + g * 4 + r][m]      = a10[r]; red[h][16 + g * 4 + r][16 + m] = a11[r];
      red[h][16 + g * 4 + r][32 + m] = a12[r]; red[h][16 + g * 4 + r][48 + m] = a13[r];
    }
    if constexpr (NEED_L) {
      if (m == 0) {
#pragma unroll
        for (int r = 0; r < 4; ++r) {
          red[h][g * 4 + r][64]      = l0a[r];
          red[h][16 + g * 4 + r][64] = l1a[r];
        }
      }
    }
  }
  __syncthreads();
  if (w & 1) {
#pragma unroll
    for (int r = 0; r < 4; ++r) {
      red[h][g * 4 + r][m]      += a00[r]; red[h][g * 4 + r][16 + m] += a01[r];
      red[h][g * 4 + r][32 + m] += a02[r]; red[h][g * 4 + r][48 + m] += a03[r];
      red[h][16 + g * 4 + r][m]      += a10[r]; red[h][16 + g * 4 + r][16 + m] += a11[r];
      red[h][16 + g * 4 + r][32 + m] += a12[r]; red[h][16 + g * 4 + r][48 + m] += a13[r];
    }
    if constexpr (NEED_L) {
      if (m == 0) {
#pragma unroll
        for (int r = 0; r < 4; ++r) {
          red[h][g * 4 + r][64]      += l0a[r];
          red[h][16 + g * 4 + r][64] += l1a[r];
        }
      }
    }
  }
  __syncthreads();
#pragma unroll
  for (int k = 0; k < 8; ++k) {
    const int e = tid + k * 256;
    Ypart[((size_t)part * NN + i0 + (e >> 6)) * 64 + (e & 63)] =
        red[0][e >> 6][e & 63] + red[1][e >> 6][e & 63];
  }
  if constexpr (NEED_L) {
    if (tid < 32)
      lpart[(size_t)part * NN + i0 + tid] = red[0][tid][64] + red[1][tid][64];
  }
}

// ---------------------------------------------------------------------------
// mid: U = sum(Ypart)/l + H1 ; Z = relu(U@wt1+bs1) ; H2 = relu(Z@W2+b2)
// 16 rows/block, grid 512. U rows read as ds_read_b128 (U padded to [68]).
// ---------------------------------------------------------------------------
__global__ __launch_bounds__(256) void mid_kernel(
    const float* __restrict__ Yp, const float* __restrict__ lp,
    const float* __restrict__ H1, const float* __restrict__ wt1,
    const float* __restrict__ bs1, const float* __restrict__ W2,
    const float* __restrict__ b2, float* __restrict__ H2,
    _Float16* __restrict__ HT2)
{
  __shared__ float sA[64][68];
  __shared__ float sB[64][68];
  __shared__ float U[16][68];
  __shared__ float sb2v[64];
  const int t = threadIdx.x;
  for (int e = t; e < 1024; e += 256) {
    const int rr = e >> 4, cc = (e << 2) & 63;
    *(f32x4*)&sA[rr][cc] = *(const f32x4*)(wt1 + (e << 2));
    *(f32x4*)&sB[rr][cc] = *(const f32x4*)(W2 + (e << 2));
  }
  if (t < 64) sb2v[t] = b2[t];
  const float bsv = bs1[0];
  const int i0 = blockIdx.x * 16;
  const int r = t >> 4, q = t & 15;
  const int i = i0 + r;
  float l = 0.f;
#pragma unroll
  for (int p = 0; p < 8; ++p) l += lp[(size_t)p * NN + i];
  const float rl = 1.0f / l;
  f32x4 ya = {0, 0, 0, 0};
#pragma unroll
  for (int p = 0; p < 8; ++p)
    ya += *(const f32x4*)(Yp + ((size_t)p * NN + i) * 64 + q * 4);
  const f32x4 h1 = *(const f32x4*)(H1 + (size_t)i * 64 + q * 4);
#pragma unroll
  for (int c = 0; c < 4; ++c) U[r][q * 4 + c] = fmaf(ya[c], rl, h1[c]);
  __syncthreads();
  float z[4];
#pragma unroll
  for (int c = 0; c < 4; ++c) z[c] = bsv;
#pragma unroll
  for (int k4 = 0; k4 < 64; k4 += 4) {
    const f32x4 u4 = *(const f32x4*)&U[r][k4];
#pragma unroll
    for (int kk = 0; kk < 4; ++kk) {
      const f32x4 sa = *(const f32x4*)&sA[k4 + kk][q * 4];
#pragma unroll
      for (int c = 0; c < 4; ++c) z[c] = fmaf(u4[kk], sa[c], z[c]);
    }
  }
  __syncthreads();
#pragma unroll
  for (int c = 0; c < 4; ++c) U[r][q * 4 + c] = fmaxf(z[c], 0.f);
  __syncthreads();
  float hv[4];
#pragma unroll
  for (int c = 0; c < 4; ++c) hv[c] = sb2v[q * 4 + c];
#pragma unroll
  for (int k4 = 0; k4 < 64; k4 += 4) {
    const f32x4 u4 = *(const f32x4*)&U[r][k4];
#pragma unroll
    for (int kk = 0; kk < 4; ++kk) {
      const f32x4 sb4 = *(const f32x4*)&sB[k4 + kk][q * 4];
#pragma unroll
      for (int c = 0; c < 4; ++c) hv[c] = fmaf(u4[kk], sb4[c], hv[c]);
    }
  }
  __syncthreads();
#pragma unroll
  for (int c = 0; c < 4; ++c) U[r][q * 4 + c] = fmaxf(hv[c], 0.f);
  __syncthreads();
  *(f32x4*)(H2 + (size_t)i0 * 64 + (t << 2)) =
      *(const f32x4*)&U[t >> 4][(t << 2) & 63];
  const int n = t >> 2, sg = (t & 3) * 4;
  h4 v;
#pragma unroll
  for (int ss = 0; ss < 4; ss++) v[ss] = (_Float16)U[sg + ss][n];
  *(h4*)(HT2 + (size_t)n * NN + i0 + sg) = v;
}

// ---------------------------------------------------------------------------
// final: V = relu((sum(Ypart)/l + H2)@wt2 + bs2); column sums -> atomicAdd.
// ---------------------------------------------------------------------------
__global__ __launch_bounds__(256) void final_kernel(
    const float* __restrict__ Yp, const float* __restrict__ lp,
    const float* __restrict__ H2, const float* __restrict__ wt2,
    const float* __restrict__ bs2, float* __restrict__ svec)
{
  __shared__ float sA[64][68];
  __shared__ float U[16][68];
  __shared__ float cred[4][64];
  const int t = threadIdx.x;
  for (int e = t; e < 1024; e += 256) {
    const int rr = e >> 4, cc = (e << 2) & 63;
    *(f32x4*)&sA[rr][cc] = *(const f32x4*)(wt2 + (e << 2));
  }
  const float bsv = bs2[0];
  const int i0 = blockIdx.x * 16;
  const int r = t >> 4, q = t & 15;
  const int i = i0 + r;
  float l = 0.f;
#pragma unroll
  for (int p = 0; p < 8; ++p) l += lp[(size_t)p * NN + i];
  const float rl = 1.0f / l;
  f32x4 ya = {0, 0, 0, 0};
#pragma unroll
  for (int p = 0; p < 8; ++p)
    ya += *(const f32x4*)(Yp + ((size_t)p * NN + i) * 64 + q * 4);
  const f32x4 h2 = *(const f32x4*)(H2 + (size_t)i * 64 + q * 4);
#pragma unroll
  for (int c = 0; c < 4; ++c) U[r][q * 4 + c] = fmaf(ya[c], rl, h2[c]);
  __syncthreads();
  float z[4];
#pragma unroll
  for (int c = 0; c < 4; ++c) z[c] = bsv;
#pragma unroll
  for (int k4 = 0; k4 < 64; k4 += 4) {
    const f32x4 u4 = *(const f32x4*)&U[r][k4];
#pragma unroll
    for (int kk = 0; kk < 4; ++kk) {
      const f32x4 sa = *(const f32x4*)&sA[k4 + kk][q * 4];
#pragma unroll
      for (int c = 0; c < 4; ++c) z[c] = fmaf(u4[kk], sa[c], z[c]);
    }
  }
  __syncthreads();
#pragma unroll
  for (int c = 0; c < 4; ++c) U[r][q * 4 + c] = fmaxf(z[c], 0.f);
  __syncthreads();
  const int col = t & 63, rg = t >> 6;
  float ps = 0.f;
#pragma unroll
  for (int rr = 0; rr < 4; rr++) ps += U[rg * 4 + rr][col];
  cred[rg][col] = ps;
  __syncthreads();
  if (t < 64)
    atomicAdd(svec + t, cred[0][t] + cred[1][t] + cred[2][t] + cred[3][t]);
}

__global__ void out_kernel(const float* __restrict__ svec,
                           const float* __restrict__ Wl,
                           const float* __restrict__ bl,
                           float* __restrict__ out)
{
  const int t = threadIdx.x;  // 64 threads
  float v = svec[t] * Wl[t];
#pragma unroll
  for (int off = 32; off > 0; off >>= 1) v += __shfl_down(v, off);
  if (t == 0) {
    const float logit = v + bl[0];
    out[0] = 1.0f / (1.0f + __builtin_amdgcn_exp2f(-logit * L2E));
  }
}

extern "C" void kernel_launch(void* const* d_in, const int* in_sizes, int n_in,
                              void* d_out, int out_size, void* d_ws,
                              size_t ws_size, hipStream_t stream)
{
  const float* x     = (const float*)d_in[0];
  const float* alpha = (const float*)d_in[1];
  const float* W1    = (const float*)d_in[2];
  const float* b1    = (const float*)d_in[3];
  const float* wt1   = (const float*)d_in[4];
  const float* bs1   = (const float*)d_in[5];
  const float* W2    = (const float*)d_in[6];
  const float* b2    = (const float*)d_in[7];
  const float* wt2   = (const float*)d_in[8];
  const float* bs2   = (const float*)d_in[9];
  const float* Wl    = (const float*)d_in[10];
  const float* bl    = (const float*)d_in[11];
  float* out = (float*)d_out;

  char* ws = (char*)d_ws;
  size_t off = 0;
  auto alloc = [&](size_t bytes) {
    void* p = ws + off;
    off = (off + bytes + 255) & ~(size_t)255;
    return p;
  };
  float* eta_s = (float*)alloc(NN * 4 + 256);
  float* phi_s = (float*)alloc(NN * 4 + 256);
  float* H1    = (float*)alloc((size_t)NN * 64 * 4);
  float* H2    = (float*)alloc((size_t)NN * 64 * 4);
  float* Ypart = (float*)alloc((size_t)8 * NN * 64 * 4);   // 16 MB
  float* lpart = (float*)alloc((size_t)8 * NN * 4);
  _Float16* HT = (_Float16*)alloc((size_t)NN * 64 * 2 + 512);
  float* svec  = (float*)alloc(64 * 4);

  prep_kernel<<<256, 256, 0, stream>>>(x, alpha, W1, b1, eta_s, phi_s, H1, HT, svec);
  attn_pass<true><<<2048, 256, 0, stream>>>(eta_s, phi_s, HT, alpha, Ypart, lpart);
  mid_kernel<<<512, 256, 0, stream>>>(Ypart, lpart, H1, wt1, bs1, W2, b2, H2, HT);
  attn_pass<false><<<2048, 256, 0, stream>>>(eta_s, phi_s, HT, alpha, Ypart, nullptr);
  final_kernel<<<512, 256, 0, stream>>>(Ypart, lpart, H2, wt2, bs2, svec);
  out_kernel<<<1, 64, 0, stream>>>(svec, Wl, bl, out);
}

// Round 5
// 167.477 us; speedup vs baseline: 1.1550x; 1.1090x over previous
//
#include <hip/hip_runtime.h>
#include <math.h>

#define NN 8192
#define L2E 1.44269504088896340736f
#define TWO_PI 6.28318530717958647693f

typedef _Float16 h8 __attribute__((ext_vector_type(8)));
typedef _Float16 h4 __attribute__((ext_vector_type(4)));
typedef float f32x4 __attribute__((ext_vector_type(4)));
typedef float f32x2 __attribute__((ext_vector_type(2)));
#define MFMA16(A, B, C) __builtin_amdgcn_mfma_f32_16x16x32_f16(A, B, C, 0, 0, 0)

// async 16B-per-lane global->LDS DMA; LDS dest is wave-uniform base + lane*16
#define GLD_LDS16(gsrc, ldst)                                          \
  __builtin_amdgcn_global_load_lds(                                    \
      (const __attribute__((address_space(1))) unsigned int*)(gsrc),   \
      (__attribute__((address_space(3))) unsigned int*)(ldst), 16, 0, 0)

union V8 { float4 v[2]; float f[8]; };

// ---------------------------------------------------------------------------
// prep: eta_s = eta*s, phi_s = phi*s (s = sqrt(alpha*log2e));
// H1 = relu(x@W1+b1) f32 row-major + f16 transposed [64][NN]. 32 rows/block.
// ---------------------------------------------------------------------------
__global__ __launch_bounds__(256) void prep_kernel(
    const float* __restrict__ x, const float* __restrict__ alpha,
    const float* __restrict__ W1, const float* __restrict__ b1,
    float* __restrict__ eta_s, float* __restrict__ phi_s,
    float* __restrict__ H1, _Float16* __restrict__ HT1,
    float* __restrict__ svec)
{
  __shared__ float sW[448];
  __shared__ float sb[64];
  __shared__ float T[32][68];
  const int t = threadIdx.x;
  if (blockIdx.x == 0 && t < 64) svec[t] = 0.f;
  for (int k = t; k < 448; k += 256) sW[k] = W1[k];
  if (t < 64) sb[t] = b1[t];
  const float s = sqrtf(alpha[0] * L2E);
  const int i0 = blockIdx.x * 32;
  const int r = t >> 3, q = t & 7;
  const int i = i0 + r;
  float xv[7];
#pragma unroll
  for (int k = 0; k < 7; k++) xv[k] = x[i * 7 + k];
  if (q == 0) { eta_s[i] = xv[1] * s; phi_s[i] = xv[2] * s; }
  __syncthreads();
#pragma unroll
  for (int c = 0; c < 8; c++) {
    const int n = q * 8 + c;
    float hv = sb[n];
#pragma unroll
    for (int k = 0; k < 7; k++) hv = fmaf(xv[k], sW[k * 64 + n], hv);
    T[r][n] = fmaxf(hv, 0.f);
  }
  __syncthreads();
  for (int e = t; e < 512; e += 256)
    *(f32x4*)(H1 + (size_t)i0 * 64 + (e << 2)) =
        *(const f32x4*)&T[e >> 4][(e << 2) & 63];
  const int n = t >> 2, sg = (t & 3) * 8;
  h8 v;
#pragma unroll
  for (int ss = 0; ss < 8; ss++) v[ss] = (_Float16)T[sg + ss][n];
  *(h8*)(HT1 + (size_t)n * NN + i0 + sg) = v;
}

// ---------------------------------------------------------------------------
// attn: 32 i-rows/block, 4-way j-split (grid 1024). 16 stages of 128 j; HT
// chunk [64 rows][128 j] staged via global_load_lds into double-buffered,
// XOR-swizzled LDS. Wave w consumes j-slice w*32..w*32+31 of each stage.
// Stage loop as 8 double-stages (no E/P copies, const addrs). E/P are
// prefetched to REGISTERS one stage ahead -> pv VALU chain has zero memory
// dependency at stage start. l via extra MFMA with ones B-frag.
// T5: s_setprio(1) around the MFMA cluster (multi-block/CU phase diversity).
// ---------------------------------------------------------------------------
template <bool NEED_L>
__global__ __launch_bounds__(256, 4) void attn_pass(
    const float* __restrict__ eta_s, const float* __restrict__ phi_s,
    const _Float16* __restrict__ HT, const float* __restrict__ alpha,
    float* __restrict__ Ypart, float* __restrict__ lpart)
{
  __shared__ __align__(16) char smem[32768];
  _Float16* stage = (_Float16*)smem;  // 2 x 16384 B
  const int tid = threadIdx.x;
  const int w = tid >> 6, lane = tid & 63, m = lane & 15, g = lane >> 4;
  const int tile = blockIdx.x >> 2, part = blockIdx.x & 3;
  const int i0 = tile << 5;
  const int jbase = part << 11;
  const float Cs = TWO_PI * sqrtf(alpha[0] * L2E);
  const float et0 = eta_s[i0 + m],      ph0 = phi_s[i0 + m];
  const float et1 = eta_s[i0 + 16 + m], ph1 = phi_s[i0 + 16 + m];

  // staging geometry: slot d = k*256+tid holds HT row (k*16 + tid>>4),
  // swizzled j-group ((tid&15) ^ (tid>>4)). Same swizzle offset for all k.
  const int r0 = tid >> 4, gq = tid & 15;
  const _Float16* sbase = HT + (size_t)r0 * NN + ((gq ^ r0) << 3) + jbase;

  f32x4 a00 = {0,0,0,0}, a01 = {0,0,0,0}, a02 = {0,0,0,0}, a03 = {0,0,0,0};
  f32x4 a10 = {0,0,0,0}, a11 = {0,0,0,0}, a12 = {0,0,0,0}, a13 = {0,0,0,0};
  f32x4 l0a = {0,0,0,0}, l1a = {0,0,0,0};
  const h8 onesv = {(_Float16)1.f, (_Float16)1.f, (_Float16)1.f, (_Float16)1.f,
                    (_Float16)1.f, (_Float16)1.f, (_Float16)1.f, (_Float16)1.f};

  const float* ep = eta_s + jbase + (w << 5) + (g << 3);
  const float* pp = phi_s + jbase + (w << 5) + (g << 3);
  V8 E0, P0, E1, P1;
  E0.v[0] = *(const float4*)ep;  E0.v[1] = *(const float4*)(ep + 4);
  P0.v[0] = *(const float4*)pp;  P0.v[1] = *(const float4*)(pp + 4);

  // prologue: stage 0 -> buf0
#pragma unroll
  for (int k = 0; k < 4; ++k)
    GLD_LDS16(sbase + (size_t)k * 16 * NN, stage + ((k * 256 + tid) << 3));
  __syncthreads();

  // frag slot (nb=0): row block m, swizzled j-group (w*4+g)^m
  const int fs = ((m << 4) + (((w << 2) | g) ^ m)) << 3;

  union AF { h8 v; decltype(__builtin_amdgcn_cvt_pkrtz(0.f, 0.f)) p[4]; };

  auto stage_compute = [&](const V8& Ec, const V8& Pc, const _Float16* cur) {
    const h8 b0 = *(const h8*)(cur + fs);
    const h8 b1 = *(const h8*)(cur + 2048 + fs);
    const h8 b2 = *(const h8*)(cur + 4096 + fs);
    const h8 b3 = *(const h8*)(cur + 6144 + fs);
    AF af0, af1;
#pragma unroll
    for (int tt = 0; tt < 8; tt += 2) {
      const f32x2 pj = {Pc.f[tt], Pc.f[tt + 1]};
      const f32x2 ej = {Ec.f[tt], Ec.f[tt + 1]};
      const f32x2 dp0 = ph0 - pj, dp1 = ph1 - pj;
      const f32x2 ad0 = {fabsf(dp0.x), fabsf(dp0.y)};
      const f32x2 ad1 = {fabsf(dp1.x), fabsf(dp1.y)};
      const f32x2 cm0 = Cs - ad0, cm1 = Cs - ad1;
      const f32x2 wr0 = {fminf(ad0.x, cm0.x), fminf(ad0.y, cm0.y)};
      const f32x2 wr1 = {fminf(ad1.x, cm1.x), fminf(ad1.y, cm1.y)};
      const f32x2 de0 = et0 - ej, de1 = et1 - ej;
      const f32x2 r20 = de0 * de0 + wr0 * wr0;
      const f32x2 r21 = de1 * de1 + wr1 * wr1;
      const f32x2 ax0 = {__builtin_amdgcn_exp2f(-r20.x),
                         __builtin_amdgcn_exp2f(-r20.y)};
      const f32x2 ax1 = {__builtin_amdgcn_exp2f(-r21.x),
                         __builtin_amdgcn_exp2f(-r21.y)};
      const f32x2 ga0 = ax0 * L2E - L2E;
      const f32x2 ga1 = ax1 * L2E - L2E;
      af0.p[tt >> 1] = __builtin_amdgcn_cvt_pkrtz(
          __builtin_amdgcn_exp2f(ga0.x), __builtin_amdgcn_exp2f(ga0.y));
      af1.p[tt >> 1] = __builtin_amdgcn_cvt_pkrtz(
          __builtin_amdgcn_exp2f(ga1.x), __builtin_amdgcn_exp2f(ga1.y));
    }
    __builtin_amdgcn_s_setprio(1);
    a00 = MFMA16(af0.v, b0, a00); a01 = MFMA16(af0.v, b1, a01);
    a02 = MFMA16(af0.v, b2, a02); a03 = MFMA16(af0.v, b3, a03);
    a10 = MFMA16(af1.v, b0, a10); a11 = MFMA16(af1.v, b1, a11);
    a12 = MFMA16(af1.v, b2, a12); a13 = MFMA16(af1.v, b3, a13);
    if constexpr (NEED_L) {
      l0a = MFMA16(af0.v, onesv, l0a);
      l1a = MFMA16(af1.v, onesv, l1a);
    }
    __builtin_amdgcn_s_setprio(0);
  };

#pragma unroll
  for (int s2 = 0; s2 < 8; ++s2) {
    // body A: compute stage 2*s2 from buf0; prefetch stage 2*s2+1 -> buf1
    {
      const _Float16* src = sbase + (2 * s2 + 1) * 128;
#pragma unroll
      for (int k = 0; k < 4; ++k)
        GLD_LDS16(src + (size_t)k * 16 * NN,
                  stage + 8192 + ((k * 256 + tid) << 3));
      E1.v[0] = *(const float4*)(ep + s2 * 256 + 128);
      E1.v[1] = *(const float4*)(ep + s2 * 256 + 132);
      P1.v[0] = *(const float4*)(pp + s2 * 256 + 128);
      P1.v[1] = *(const float4*)(pp + s2 * 256 + 132);
      stage_compute(E0, P0, stage);
      __syncthreads();  // drains prefetch + all frag reads of buf0
    }
    // body B: compute stage 2*s2+1 from buf1; prefetch 2*s2+2 -> buf0
    {
      if (s2 < 7) {
        const _Float16* src = sbase + (2 * s2 + 2) * 128;
#pragma unroll
        for (int k = 0; k < 4; ++k)
          GLD_LDS16(src + (size_t)k * 16 * NN,
                    stage + ((k * 256 + tid) << 3));
        E0.v[0] = *(const float4*)(ep + s2 * 256 + 256);
        E0.v[1] = *(const float4*)(ep + s2 * 256 + 260);
        P0.v[0] = *(const float4*)(pp + s2 * 256 + 256);
        P0.v[1] = *(const float4*)(pp + s2 * 256 + 260);
      }
      stage_compute(E1, P1, stage + 8192);
      __syncthreads();
    }
  }

  // cross-wave reduction (aliases stage; all stage reads completed above).
  // D layout: col = lane&15, row = (lane>>4)*4 + reg. Col 64 carries l
  // (= rowsum from the ones-MFMA; identical across lanes m, so m==0 writes).
  typedef float Red2[32][66];
  Red2* red = (Red2*)smem;                  // 2 x 8448 B
  const int h = w >> 1;
  if ((w & 1) == 0) {
#pragma unroll
    for (int r = 0; r < 4; ++r) {
      red[h][g * 4 + r][m]      = a00[r]; red[h][g * 4 + r][16 + m] = a01[r];
      red[h][g * 4 + r][32 + m] = a02[r]; red[h][g * 4 + r][48 + m] = a03[r];
      red[h][16 + g * 4 + r][m]      = a10[r]; red[h][16 + g * 4 + r][16 + m] = a11[r];
      red[h][16 + g * 4 + r][32 + m] = a12[r]; red[h][16 + g * 4 + r][48 + m] = a13[r];
    }
    if constexpr (NEED_L) {
      if (m == 0) {
#pragma unroll
        for (int r = 0; r < 4; ++r) {
          red[h][g * 4 + r][64]      = l0a[r];
          red[h][16 + g * 4 + r][64] = l1a[r];
        }
      }
    }
  }
  __syncthreads();
  if (w & 1) {
#pragma unroll
    for (int r = 0; r < 4; ++r) {
      red[h][g * 4 + r][m]      += a00[r]; red[h][g * 4 + r][16 + m] += a01[r];
      red[h][g * 4 + r][32 + m] += a02[r]; red[h][g * 4 + r][48 + m] += a03[r];
      red[h][16 + g * 4 + r][m]      += a10[r]; red[h][16 + g * 4 + r][16 + m] += a11[r];
      red[h][16 + g * 4 + r][32 + m] += a12[r]; red[h][16 + g * 4 + r][48 + m] += a13[r];
    }
    if constexpr (NEED_L) {
      if (m == 0) {
#pragma unroll
        for (int r = 0; r < 4; ++r) {
          red[h][g * 4 + r][64]      += l0a[r];
          red[h][16 + g * 4 + r][64] += l1a[r];
        }
      }
    }
  }
  __syncthreads();
#pragma unroll
  for (int k = 0; k < 8; ++k) {
    const int e = tid + k * 256;
    Ypart[((size_t)part * NN + i0 + (e >> 6)) * 64 + (e & 63)] =
        red[0][e >> 6][e & 63] + red[1][e >> 6][e & 63];
  }
  if constexpr (NEED_L) {
    if (tid < 32)
      lpart[(size_t)part * NN + i0 + tid] = red[0][tid][64] + red[1][tid][64];
  }
}

// ---------------------------------------------------------------------------
// mid: U = sum(Ypart)/l + H1 ; Z = relu(U@wt1+bs1) ; H2 = relu(Z@W2+b2)
// 16 rows/block, grid 512. U rows read as ds_read_b128 (U padded to [68]).
// ---------------------------------------------------------------------------
__global__ __launch_bounds__(256) void mid_kernel(
    const float* __restrict__ Yp, const float* __restrict__ lp,
    const float* __restrict__ H1, const float* __restrict__ wt1,
    const float* __restrict__ bs1, const float* __restrict__ W2,
    const float* __restrict__ b2, float* __restrict__ H2,
    _Float16* __restrict__ HT2)
{
  __shared__ float sA[64][68];
  __shared__ float sB[64][68];
  __shared__ float U[16][68];
  __shared__ float sb2v[64];
  const int t = threadIdx.x;
  for (int e = t; e < 1024; e += 256) {
    const int rr = e >> 4, cc = (e << 2) & 63;
    *(f32x4*)&sA[rr][cc] = *(const f32x4*)(wt1 + (e << 2));
    *(f32x4*)&sB[rr][cc] = *(const f32x4*)(W2 + (e << 2));
  }
  if (t < 64) sb2v[t] = b2[t];
  const float bsv = bs1[0];
  const int i0 = blockIdx.x * 16;
  const int r = t >> 4, q = t & 15;
  const int i = i0 + r;
  float l = 0.f;
#pragma unroll
  for (int p = 0; p < 4; ++p) l += lp[(size_t)p * NN + i];
  const float rl = 1.0f / l;
  f32x4 ya = {0, 0, 0, 0};
#pragma unroll
  for (int p = 0; p < 4; ++p)
    ya += *(const f32x4*)(Yp + ((size_t)p * NN + i) * 64 + q * 4);
  const f32x4 h1 = *(const f32x4*)(H1 + (size_t)i * 64 + q * 4);
#pragma unroll
  for (int c = 0; c < 4; ++c) U[r][q * 4 + c] = fmaf(ya[c], rl, h1[c]);
  __syncthreads();
  float z[4];
#pragma unroll
  for (int c = 0; c < 4; ++c) z[c] = bsv;
#pragma unroll
  for (int k4 = 0; k4 < 64; k4 += 4) {
    const f32x4 u4 = *(const f32x4*)&U[r][k4];
#pragma unroll
    for (int kk = 0; kk < 4; ++kk) {
      const f32x4 sa = *(const f32x4*)&sA[k4 + kk][q * 4];
#pragma unroll
      for (int c = 0; c < 4; ++c) z[c] = fmaf(u4[kk], sa[c], z[c]);
    }
  }
  __syncthreads();
#pragma unroll
  for (int c = 0; c < 4; ++c) U[r][q * 4 + c] = fmaxf(z[c], 0.f);
  __syncthreads();
  float hv[4];
#pragma unroll
  for (int c = 0; c < 4; ++c) hv[c] = sb2v[q * 4 + c];
#pragma unroll
  for (int k4 = 0; k4 < 64; k4 += 4) {
    const f32x4 u4 = *(const f32x4*)&U[r][k4];
#pragma unroll
    for (int kk = 0; kk < 4; ++kk) {
      const f32x4 sb4 = *(const f32x4*)&sB[k4 + kk][q * 4];
#pragma unroll
      for (int c = 0; c < 4; ++c) hv[c] = fmaf(u4[kk], sb4[c], hv[c]);
    }
  }
  __syncthreads();
#pragma unroll
  for (int c = 0; c < 4; ++c) U[r][q * 4 + c] = fmaxf(hv[c], 0.f);
  __syncthreads();
  *(f32x4*)(H2 + (size_t)i0 * 64 + (t << 2)) =
      *(const f32x4*)&U[t >> 4][(t << 2) & 63];
  const int n = t >> 2, sg = (t & 3) * 4;
  h4 v;
#pragma unroll
  for (int ss = 0; ss < 4; ss++) v[ss] = (_Float16)U[sg + ss][n];
  *(h4*)(HT2 + (size_t)n * NN + i0 + sg) = v;
}

// ---------------------------------------------------------------------------
// final: V = relu((sum(Ypart)/l + H2)@wt2 + bs2); column sums -> atomicAdd.
// ---------------------------------------------------------------------------
__global__ __launch_bounds__(256) void final_kernel(
    const float* __restrict__ Yp, const float* __restrict__ lp,
    const float* __restrict__ H2, const float* __restrict__ wt2,
    const float* __restrict__ bs2, float* __restrict__ svec)
{
  __shared__ float sA[64][68];
  __shared__ float U[16][68];
  __shared__ float cred[4][64];
  const int t = threadIdx.x;
  for (int e = t; e < 1024; e += 256) {
    const int rr = e >> 4, cc = (e << 2) & 63;
    *(f32x4*)&sA[rr][cc] = *(const f32x4*)(wt2 + (e << 2));
  }
  const float bsv = bs2[0];
  const int i0 = blockIdx.x * 16;
  const int r = t >> 4, q = t & 15;
  const int i = i0 + r;
  float l = 0.f;
#pragma unroll
  for (int p = 0; p < 4; ++p) l += lp[(size_t)p * NN + i];
  const float rl = 1.0f / l;
  f32x4 ya = {0, 0, 0, 0};
#pragma unroll
  for (int p = 0; p < 4; ++p)
    ya += *(const f32x4*)(Yp + ((size_t)p * NN + i) * 64 + q * 4);
  const f32x4 h2 = *(const f32x4*)(H2 + (size_t)i * 64 + q * 4);
#pragma unroll
  for (int c = 0; c < 4; ++c) U[r][q * 4 + c] = fmaf(ya[c], rl, h2[c]);
  __syncthreads();
  float z[4];
#pragma unroll
  for (int c = 0; c < 4; ++c) z[c] = bsv;
#pragma unroll
  for (int k4 = 0; k4 < 64; k4 += 4) {
    const f32x4 u4 = *(const f32x4*)&U[r][k4];
#pragma unroll
    for (int kk = 0; kk < 4; ++kk) {
      const f32x4 sa = *(const f32x4*)&sA[k4 + kk][q * 4];
#pragma unroll
      for (int c = 0; c < 4; ++c) z[c] = fmaf(u4[kk], sa[c], z[c]);
    }
  }
  __syncthreads();
#pragma unroll
  for (int c = 0; c < 4; ++c) U[r][q * 4 + c] = fmaxf(z[c], 0.f);
  __syncthreads();
  const int col = t & 63, rg = t >> 6;
  float ps = 0.f;
#pragma unroll
  for (int rr = 0; rr < 4; rr++) ps += U[rg * 4 + rr][col];
  cred[rg][col] = ps;
  __syncthreads();
  if (t < 64)
    atomicAdd(svec + t, cred[0][t] + cred[1][t] + cred[2][t] + cred[3][t]);
}

__global__ void out_kernel(const float* __restrict__ svec,
                           const float* __restrict__ Wl,
                           const float* __restrict__ bl,
                           float* __restrict__ out)
{
  const int t = threadIdx.x;  // 64 threads
  float v = svec[t] * Wl[t];
#pragma unroll
  for (int off = 32; off > 0; off >>= 1) v += __shfl_down(v, off);
  if (t == 0) {
    const float logit = v + bl[0];
    out[0] = 1.0f / (1.0f + __builtin_amdgcn_exp2f(-logit * L2E));
  }
}

extern "C" void kernel_launch(void* const* d_in, const int* in_sizes, int n_in,
                              void* d_out, int out_size, void* d_ws,
                              size_t ws_size, hipStream_t stream)
{
  const float* x     = (const float*)d_in[0];
  const float* alpha = (const float*)d_in[1];
  const float* W1    = (const float*)d_in[2];
  const float* b1    = (const float*)d_in[3];
  const float* wt1   = (const float*)d_in[4];
  const float* bs1   = (const float*)d_in[5];
  const float* W2    = (const float*)d_in[6];
  const float* b2    = (const float*)d_in[7];
  const float* wt2   = (const float*)d_in[8];
  const float* bs2   = (const float*)d_in[9];
  const float* Wl    = (const float*)d_in[10];
  const float* bl    = (const float*)d_in[11];
  float* out = (float*)d_out;

  char* ws = (char*)d_ws;
  size_t off = 0;
  auto alloc = [&](size_t bytes) {
    void* p = ws + off;
    off = (off + bytes + 255) & ~(size_t)255;
    return p;
  };
  float* eta_s = (float*)alloc(NN * 4 + 256);
  float* phi_s = (float*)alloc(NN * 4 + 256);
  float* H1    = (float*)alloc((size_t)NN * 64 * 4);
  float* H2    = (float*)alloc((size_t)NN * 64 * 4);
  float* Ypart = (float*)alloc((size_t)4 * NN * 64 * 4);   // 8 MB
  float* lpart = (float*)alloc((size_t)4 * NN * 4);
  _Float16* HT = (_Float16*)alloc((size_t)NN * 64 * 2 + 512);
  float* svec  = (float*)alloc(64 * 4);

  prep_kernel<<<256, 256, 0, stream>>>(x, alpha, W1, b1, eta_s, phi_s, H1, HT, svec);
  attn_pass<true><<<1024, 256, 0, stream>>>(eta_s, phi_s, HT, alpha, Ypart, lpart);
  mid_kernel<<<512, 256, 0, stream>>>(Ypart, lpart, H1, wt1, bs1, W2, b2, H2, HT);
  attn_pass<false><<<1024, 256, 0, stream>>>(eta_s, phi_s, HT, alpha, Ypart, nullptr);
  final_kernel<<<512, 256, 0, stream>>>(Ypart, lpart, H2, wt2, bs2, svec);
  out_kernel<<<1, 64, 0, stream>>>(svec, Wl, bl, out);
}